// Round 10
// baseline (379.380 us; speedup 1.0000x reference)
//
#include <hip/hip_runtime.h>
#include <math.h>

#define NN 50000
#define NE 800000
#define D  256
#define SCB 196  // ceil(NN/256)

typedef unsigned short u16;
typedef __attribute__((ext_vector_type(8))) short short8;
typedef __attribute__((ext_vector_type(8))) unsigned short u16x8;
typedef __attribute__((ext_vector_type(4))) float f32x4;

// f32 -> bf16 round-to-nearest-even
__device__ __forceinline__ u16 f2b(float f) {
    unsigned u = __float_as_uint(f);
    return (u16)((u + 0x7FFFu + ((u >> 16) & 1u)) >> 16);
}
__device__ __forceinline__ float b2f(u16 b) {
    return __uint_as_float(((unsigned)b) << 16);
}

// async global->LDS, 16 bytes per lane; LDS dest = wave-uniform base + lane*16
__device__ __forceinline__ void gl16(const u16* g, u16* l) {
    __builtin_amdgcn_global_load_lds(
        (const __attribute__((address_space(1))) void*)g,
        (__attribute__((address_space(3))) void*)l, 16, 0, 0);
}

// ---------------- CSR build ----------------
// 4 edges per thread: 4 independent atomics in flight (latency hiding)
__global__ void degree_kernel(const int* __restrict__ dst, int* __restrict__ deg) {
    int e0 = (blockIdx.x * blockDim.x + threadIdx.x) * 4;
    if (e0 + 3 < NE) {
        int4 d = *(const int4*)&dst[e0];
        atomicAdd(&deg[d.x], 1);
        atomicAdd(&deg[d.y], 1);
        atomicAdd(&deg[d.z], 1);
        atomicAdd(&deg[d.w], 1);
    } else {
        for (int e = e0; e < NE; e++) atomicAdd(&deg[dst[e]], 1);
    }
}

__global__ void scanA_kernel(const int* __restrict__ deg, int* __restrict__ partial) {
    int t = threadIdx.x;
    int i = blockIdx.x * 256 + t;
    int v = (i < NN) ? deg[i] : 0;
#pragma unroll
    for (int o = 32; o; o >>= 1) v += __shfl_xor(v, o);
    __shared__ int sm[4];
    if ((t & 63) == 0) sm[t >> 6] = v;
    __syncthreads();
    if (t == 0) partial[blockIdx.x] = sm[0] + sm[1] + sm[2] + sm[3];
}

__global__ void scanB_kernel(const int* __restrict__ partial, int* __restrict__ base,
                             int* __restrict__ offs) {
    __shared__ int sm[256];
    int t = threadIdx.x;
    int v = (t < SCB) ? partial[t] : 0;
    sm[t] = v;
    __syncthreads();
    for (int off = 1; off < 256; off <<= 1) {
        int u = 0;
        if (t >= off) u = sm[t - off];
        __syncthreads();
        sm[t] += u;
        __syncthreads();
    }
    if (t < SCB) base[t] = sm[t] - v;
    if (t == 255) offs[NN] = sm[255];
}

__global__ void scanC_kernel(const int* __restrict__ deg, const int* __restrict__ base,
                             int* __restrict__ offs, int* __restrict__ cur) {
    __shared__ int sm[256];
    int t = threadIdx.x;
    int i = blockIdx.x * 256 + t;
    int v = (i < NN) ? deg[i] : 0;
    sm[t] = v;
    __syncthreads();
    for (int off = 1; off < 256; off <<= 1) {
        int u = 0;
        if (t >= off) u = sm[t - off];
        __syncthreads();
        sm[t] += u;
        __syncthreads();
    }
    int o = base[blockIdx.x] + sm[t] - v;
    if (i < NN) {
        offs[i] = o;
        cur[i] = o;
    }
}

// 4 edges per thread: int4 loads, 4 independent atomic+store chains
__global__ void fill_kernel(const int* __restrict__ src, const int* __restrict__ dst,
                            int* __restrict__ cur, int* __restrict__ csr) {
    int e0 = (blockIdx.x * blockDim.x + threadIdx.x) * 4;
    if (e0 + 3 < NE) {
        int4 d = *(const int4*)&dst[e0];
        int4 s = *(const int4*)&src[e0];
        int p0 = atomicAdd(&cur[d.x], 1);
        int p1 = atomicAdd(&cur[d.y], 1);
        int p2 = atomicAdd(&cur[d.z], 1);
        int p3 = atomicAdd(&cur[d.w], 1);
        csr[p0] = s.x;
        csr[p1] = s.y;
        csr[p2] = s.z;
        csr[p3] = s.w;
    } else {
        for (int e = e0; e < NE; e++) {
            int pos = atomicAdd(&cur[dst[e]], 1);
            csr[pos] = src[e];
        }
    }
}

// ---------------- weight pack ----------------
__global__ void wconv_kernel(const float* __restrict__ W1l, const float* __restrict__ W1r,
                             const float* __restrict__ W2l, const float* __restrict__ W2r,
                             u16* __restrict__ Wcat1, u16* __restrict__ Wcat2) {
    int r = blockIdx.x;
    int j = threadIdx.x;
    Wcat1[r * 512 + j]       = f2b(W1l[r * 256 + j]);
    Wcat1[r * 512 + 256 + j] = f2b(W1r[r * 256 + j]);
    Wcat2[r * 512 + j]       = f2b(W2l[r * 256 + j]);
    Wcat2[r * 512 + 256 + j] = f2b(W2r[r * 256 + j]);
}

// ---------------- x (f32) -> Acat right half (bf16) ----------------
__global__ void xconv_kernel(const float* __restrict__ x, u16* __restrict__ Acat) {
    int idx = blockIdx.x * blockDim.x + threadIdx.x;
    int r = idx >> 6;
    int c4 = (idx & 63) * 4;
    float4 v = *(const float4*)&x[(size_t)r * 256 + c4];
    ushort4 o;
    o.x = f2b(v.x); o.y = f2b(v.y); o.z = f2b(v.z); o.w = f2b(v.w);
    *(ushort4*)&Acat[(size_t)r * 512 + 256 + c4] = o;
}

// ---------------- mean aggregation: one wave per node, 8 gathers in flight --
__global__ __launch_bounds__(256)
void agg_kernel(const u16* __restrict__ Acat, const int* __restrict__ csr,
                const int* __restrict__ offs, u16* __restrict__ AcatW) {
    int wid = (blockIdx.x * blockDim.x + threadIdx.x) >> 6;
    int lane = threadIdx.x & 63;
    if (wid >= NN) return;
    int beg = offs[wid];
    int end = offs[wid + 1];
    int deg = end - beg;
    int half = lane >> 5;
    int lc = (lane & 31) * 8;
    int mid = beg + ((deg + 1) >> 1);
    int e  = half ? mid : beg;
    int hi = half ? end : mid;
    float a[8] = {0.f, 0.f, 0.f, 0.f, 0.f, 0.f, 0.f, 0.f};
    for (; e + 7 < hi; e += 8) {
        int s0 = csr[e + 0], s1 = csr[e + 1], s2 = csr[e + 2], s3 = csr[e + 3];
        int s4 = csr[e + 4], s5 = csr[e + 5], s6 = csr[e + 6], s7 = csr[e + 7];
        u16x8 v0 = *(const u16x8*)&Acat[(size_t)s0 * 512 + 256 + lc];
        u16x8 v1 = *(const u16x8*)&Acat[(size_t)s1 * 512 + 256 + lc];
        u16x8 v2 = *(const u16x8*)&Acat[(size_t)s2 * 512 + 256 + lc];
        u16x8 v3 = *(const u16x8*)&Acat[(size_t)s3 * 512 + 256 + lc];
        u16x8 v4 = *(const u16x8*)&Acat[(size_t)s4 * 512 + 256 + lc];
        u16x8 v5 = *(const u16x8*)&Acat[(size_t)s5 * 512 + 256 + lc];
        u16x8 v6 = *(const u16x8*)&Acat[(size_t)s6 * 512 + 256 + lc];
        u16x8 v7 = *(const u16x8*)&Acat[(size_t)s7 * 512 + 256 + lc];
#pragma unroll
        for (int i = 0; i < 8; i++)
            a[i] += ((b2f(v0[i]) + b2f(v1[i])) + (b2f(v2[i]) + b2f(v3[i]))) +
                    ((b2f(v4[i]) + b2f(v5[i])) + (b2f(v6[i]) + b2f(v7[i])));
    }
    for (; e + 3 < hi; e += 4) {
        int s0 = csr[e + 0], s1 = csr[e + 1], s2 = csr[e + 2], s3 = csr[e + 3];
        u16x8 v0 = *(const u16x8*)&Acat[(size_t)s0 * 512 + 256 + lc];
        u16x8 v1 = *(const u16x8*)&Acat[(size_t)s1 * 512 + 256 + lc];
        u16x8 v2 = *(const u16x8*)&Acat[(size_t)s2 * 512 + 256 + lc];
        u16x8 v3 = *(const u16x8*)&Acat[(size_t)s3 * 512 + 256 + lc];
#pragma unroll
        for (int i = 0; i < 8; i++)
            a[i] += (b2f(v0[i]) + b2f(v1[i])) + (b2f(v2[i]) + b2f(v3[i]));
    }
    for (; e < hi; e++) {
        int s0 = csr[e];
        u16x8 v0 = *(const u16x8*)&Acat[(size_t)s0 * 512 + 256 + lc];
#pragma unroll
        for (int i = 0; i < 8; i++) a[i] += b2f(v0[i]);
    }
#pragma unroll
    for (int i = 0; i < 8; i++) a[i] += __shfl_xor(a[i], 32);
    float sc = (deg > 0) ? 1.0f / (float)deg : 0.0f;
    if (half == 0) {
        u16x8 o;
#pragma unroll
        for (int i = 0; i < 8; i++) o[i] = f2b(a[i] * sc);
        *(u16x8*)&AcatW[(size_t)wid * 512 + lc] = o;
    }
}

// ---------------- MFMA GEMM: C[NN][256] = A[NN][512] @ W[256][512]^T + bias
// 4-buffer LDS ring, counted vmcnt, raw barrier (R8 pipeline).
// STATS=1: fused per-column sum/sumsq into stats[] via per-n register
// accumulators; store nest kept in R8's (m,n,j) order for write-combining.
template<int BF16_OUT, int STATS>
__global__ __launch_bounds__(256)
void mfma_gemm_kernel(const u16* __restrict__ A, const u16* __restrict__ W,
                      const float* __restrict__ bias, void* __restrict__ Cout,
                      float* __restrict__ stats) {
    __shared__ u16 As[4][128 * 32];
    __shared__ u16 Bs[4][128 * 32];
    const int tid = threadIdx.x;
    const int l = tid & 63;
    const int wid = tid >> 6;
    const int wr = wid >> 1, wc = wid & 1;
    const int row0 = blockIdx.x * 128;
    const int col0 = blockIdx.y * 128;

    const u16* aptr[2];
    const u16* bptr[2];
#pragma unroll
    for (int i = 0; i < 2; i++) {
        int row = wid * 32 + i * 16 + (l >> 2);
        int kg = (l & 3) ^ ((row >> 1) & 3);   // pre-swizzled k-group (source side)
        int ra = row0 + row;
        if (ra > NN - 1) ra = NN - 1;
        aptr[i] = A + (size_t)ra * 512 + kg * 8;
        bptr[i] = W + (size_t)(col0 + row) * 512 + kg * 8;
    }

    f32x4 acc[4][4] = {};

#define STAGE(b, t)                                                          \
    do {                                                                     \
        _Pragma("unroll") for (int i_ = 0; i_ < 2; i_++) {                   \
            u16* al = &As[b][(wid * 32 + i_ * 16) * 32];                     \
            u16* bl = &Bs[b][(wid * 32 + i_ * 16) * 32];                     \
            gl16(aptr[i_] + (t) * 32, al);                                   \
            gl16(bptr[i_] + (t) * 32, bl);                                   \
        }                                                                    \
    } while (0)

    STAGE(0, 0);
    STAGE(1, 1);

    const int kq = l >> 4;
    const int sw = ((l & 15) >> 1) & 3;
#pragma unroll
    for (int t = 0; t < 16; t++) {
        if (t + 2 < 16) STAGE((t + 2) & 3, t + 2);

        if (t < 14)       asm volatile("s_waitcnt vmcnt(8)" ::: "memory");
        else if (t == 14) asm volatile("s_waitcnt vmcnt(4)" ::: "memory");
        else              asm volatile("s_waitcnt vmcnt(0)" ::: "memory");
        __builtin_amdgcn_s_barrier();
        __builtin_amdgcn_sched_barrier(0);

        short8 af[4], bf[4];
#pragma unroll
        for (int m = 0; m < 4; m++) {
            int row = wr * 64 + m * 16 + (l & 15);
            af[m] = *(const short8*)&As[t & 3][row * 32 + (kq ^ sw) * 8];
        }
#pragma unroll
        for (int n = 0; n < 4; n++) {
            int row = wc * 64 + n * 16 + (l & 15);
            bf[n] = *(const short8*)&Bs[t & 3][row * 32 + (kq ^ sw) * 8];
        }
#pragma unroll
        for (int m = 0; m < 4; m++)
#pragma unroll
            for (int n = 0; n < 4; n++)
                acc[m][n] = __builtin_amdgcn_mfma_f32_16x16x32_bf16(
                    af[m], bf[n], acc[m][n], 0, 0, 0);
    }
#undef STAGE

    // epilogue: C/D layout col = lane&15, row = (lane>>4)*4 + j
    // store order (m,n,j) = R8's write-combine-friendly nest.
    const int cq = l >> 4;
    const int cc = l & 15;
    float t0[4] = {0.f, 0.f, 0.f, 0.f};
    float t1[4] = {0.f, 0.f, 0.f, 0.f};
#pragma unroll
    for (int m = 0; m < 4; m++) {
#pragma unroll
        for (int n = 0; n < 4; n++) {
            int c = col0 + wc * 64 + n * 16 + cc;
#pragma unroll
            for (int j = 0; j < 4; j++) {
                int r = row0 + wr * 64 + m * 16 + cq * 4 + j;
                if (r < NN) {
                    float v = acc[m][n][j] + bias[c];
                    if (BF16_OUT)
                        ((u16*)Cout)[(size_t)r * 256 + c] = f2b(v);
                    else
                        ((float*)Cout)[(size_t)r * 256 + c] = v;
                    if (STATS) { t0[n] += v; t1[n] += v * v; }
                }
            }
        }
    }
    if (STATS) {
#pragma unroll
        for (int n = 0; n < 4; n++) {
            int c = col0 + wc * 64 + n * 16 + cc;
            float s0 = t0[n], s1 = t1[n];
            s0 += __shfl_xor(s0, 16); s1 += __shfl_xor(s1, 16);
            s0 += __shfl_xor(s0, 32); s1 += __shfl_xor(s1, 32);
            if (cq == 0) {
                atomicAdd(&stats[c], s0);
                atomicAdd(&stats[256 + c], s1);
            }
        }
    }
}

__global__ void bnfin_kernel(const float* __restrict__ stats,
                             const float* __restrict__ gamma,
                             const float* __restrict__ beta,
                             float* __restrict__ scale,
                             float* __restrict__ shift) {
    int j = threadIdx.x;
    const float invN = 1.0f / (float)NN;
    float mu = stats[j] * invN;
    float var = stats[256 + j] * invN - mu * mu;
    float sc = gamma[j] * rsqrtf(var + 1e-5f);
    scale[j] = sc;
    shift[j] = beta[j] - mu * sc;
}

// ---------------- BN + ReLU ----------------
__global__ void bnrelu_kernel(const u16* __restrict__ hb,
                              const float* __restrict__ scale,
                              const float* __restrict__ shift,
                              u16* __restrict__ Acat) {
    int idx = blockIdx.x * blockDim.x + threadIdx.x;
    int r = idx >> 5;
    int c8 = (idx & 31) * 8;
    u16x8 v = *(const u16x8*)&hb[(size_t)r * 256 + c8];
    u16x8 o;
#pragma unroll
    for (int i = 0; i < 8; i++) {
        float f = b2f(v[i]) * scale[c8 + i] + shift[c8 + i];
        o[i] = f2b(fmaxf(f, 0.f));
    }
    *(u16x8*)&Acat[(size_t)r * 512 + 256 + c8] = o;
}

// ---------------- row L2 normalize + fused column-sum ------------------
__global__ __launch_bounds__(512)
void l2norm_kernel(float* __restrict__ out, float* __restrict__ gsum) {
    __shared__ float sm[8 * 256];
    int wave = threadIdx.x >> 6;   // 0..7
    int lane = threadIdx.x & 63;
    float c0 = 0.f, c1 = 0.f, c2 = 0.f, c3 = 0.f;
    for (int r = blockIdx.x * 8 + wave; r < NN; r += gridDim.x * 8) {
        float4 v = *(float4*)&out[(size_t)r * 256 + lane * 4];
        float sq = v.x * v.x + v.y * v.y + v.z * v.z + v.w * v.w;
#pragma unroll
        for (int o = 32; o; o >>= 1) sq += __shfl_xor(sq, o);
        float invn = 1.0f / fmaxf(sqrtf(sq), 1e-12f);
        v.x *= invn; v.y *= invn; v.z *= invn; v.w *= invn;
        *(float4*)&out[(size_t)r * 256 + lane * 4] = v;
        c0 += v.x; c1 += v.y; c2 += v.z; c3 += v.w;
    }
    *(float4*)&sm[wave * 256 + lane * 4] = make_float4(c0, c1, c2, c3);
    __syncthreads();
    int t = threadIdx.x;
    if (t < 256) {
        float s = 0.f;
#pragma unroll
        for (int w = 0; w < 8; w++) s += sm[w * 256 + t];
        atomicAdd(&gsum[t], s);
    }
}

__global__ void graph_kernel(const float* __restrict__ gsum, float* __restrict__ gout) {
    __shared__ float wsum[4];
    int j = threadIdx.x;
    float v = gsum[j] * (1.0f / (float)NN);
    float sq = v * v;
#pragma unroll
    for (int o = 32; o; o >>= 1) sq += __shfl_xor(sq, o);
    if ((j & 63) == 0) wsum[j >> 6] = sq;
    __syncthreads();
    float tot = wsum[0] + wsum[1] + wsum[2] + wsum[3];
    gout[j] = v / fmaxf(sqrtf(tot), 1e-12f);
}

extern "C" void kernel_launch(void* const* d_in, const int* in_sizes, int n_in,
                              void* d_out, int out_size, void* d_ws, size_t ws_size,
                              hipStream_t stream) {
    const float* x      = (const float*)d_in[0];
    const float* W1_l   = (const float*)d_in[1];
    const float* b1_l   = (const float*)d_in[2];
    const float* W1_r   = (const float*)d_in[3];
    const float* W2_l   = (const float*)d_in[4];
    const float* b2_l   = (const float*)d_in[5];
    const float* W2_r   = (const float*)d_in[6];
    const float* gamma1 = (const float*)d_in[7];
    const float* beta1  = (const float*)d_in[8];
    const int*   eidx   = (const int*)d_in[9];
    const int* src = eidx;
    const int* dst = eidx + NE;

    char* wsb = (char*)d_ws;
    int*   deg   = (int*)(wsb + 0);
    int*   offs  = (int*)(wsb + 200000);
    int*   cur   = (int*)(wsb + 400004);
    int*   csr   = (int*)(wsb + 600004);
    int*   part  = (int*)(wsb + 3800064);
    int*   base  = (int*)(wsb + 3801088);
    float* stats = (float*)(wsb + 3802112);
    float* gsum  = (float*)(wsb + 3804160);
    float* scale = (float*)(wsb + 3805184);
    float* shift = (float*)(wsb + 3806208);
    u16*   Wcat1 = (u16*)(wsb + 3807232);
    u16*   Wcat2 = (u16*)(wsb + 4069376);
    u16*   hb    = (u16*)(wsb + 4331520);
    u16*   Acat  = (u16*)(wsb + 29931520);
    float* out   = (float*)d_out;
    float* gout  = out + (size_t)NN * 256;

    hipMemsetAsync(deg, 0, NN * sizeof(int), stream);
    hipMemsetAsync(stats, 0, 3072, stream);  // stats + gsum

    wconv_kernel<<<256, 256, 0, stream>>>(W1_l, W1_r, W2_l, W2_r, Wcat1, Wcat2);
    xconv_kernel<<<12500, 256, 0, stream>>>(x, Acat);

    degree_kernel<<<(NE / 4 + 255) / 256, 256, 0, stream>>>(dst, deg);
    scanA_kernel<<<SCB, 256, 0, stream>>>(deg, part);
    scanB_kernel<<<1, 256, 0, stream>>>(part, base, offs);
    scanC_kernel<<<SCB, 256, 0, stream>>>(deg, base, offs, cur);
    fill_kernel<<<(NE / 4 + 255) / 256, 256, 0, stream>>>(src, dst, cur, csr);

    dim3 ggrid((NN + 127) / 128, 2);

    // layer 1 (stats fused into GEMM epilogue)
    agg_kernel<<<12500, 256, 0, stream>>>(Acat, csr, offs, Acat);
    mfma_gemm_kernel<1, 1><<<ggrid, 256, 0, stream>>>(Acat, Wcat1, b1_l, hb, stats);
    bnfin_kernel<<<1, 256, 0, stream>>>(stats, gamma1, beta1, scale, shift);
    bnrelu_kernel<<<6250, 256, 0, stream>>>(hb, scale, shift, Acat);

    // layer 2
    agg_kernel<<<12500, 256, 0, stream>>>(Acat, csr, offs, Acat);
    mfma_gemm_kernel<0, 0><<<ggrid, 256, 0, stream>>>(Acat, Wcat2, b2_l, out, stats);

    // outputs
    l2norm_kernel<<<1024, 512, 0, stream>>>(out, gsum);
    graph_kernel<<<1, 256, 0, stream>>>(gsum, gout);
}